// Round 1
// baseline (2941.988 us; speedup 1.0000x reference)
//
#include <hip/hip_runtime.h>

// Problem constants (from reference): B=16, N=1024 (=32x32), DIM=768, HEADS=8,
// CH=96, HIDDEN=3072.
#define BATCH 16
#define SEQ   1024
#define DIM   768
#define NHEAD 8
#define CHD   96
#define HID   3072
#define MTOT  (BATCH * SEQ)   // 16384

using u16 = unsigned short;

__device__ inline float bf2f(u16 u) {
    union { unsigned int i; float f; } v; v.i = ((unsigned int)u) << 16; return v.f;
}
__device__ inline u16 f2bf(float f) {
    union { float f; unsigned int i; } v; v.f = f;
    unsigned int r = v.i + 0x7FFFu + ((v.i >> 16) & 1u);
    return (u16)(r >> 16);
}

__device__ inline void load4(const float* __restrict__ p, float* d) {
    float4 v = *reinterpret_cast<const float4*>(p);
    d[0] = v.x; d[1] = v.y; d[2] = v.z; d[3] = v.w;
}
__device__ inline void load4(const u16* __restrict__ p, float* d) {
    uint2 v = *reinterpret_cast<const uint2*>(p);
    d[0] = bf2f((u16)(v.x & 0xffff)); d[1] = bf2f((u16)(v.x >> 16));
    d[2] = bf2f((u16)(v.y & 0xffff)); d[3] = bf2f((u16)(v.y >> 16));
}
__device__ inline void store4(float* p, const float* v) {
    *reinterpret_cast<float4*>(p) = make_float4(v[0], v[1], v[2], v[3]);
}
__device__ inline void store4(u16* p, const float* v) {
    uint2 o;
    o.x = (unsigned int)f2bf(v[0]) | ((unsigned int)f2bf(v[1]) << 16);
    o.y = (unsigned int)f2bf(v[2]) | ((unsigned int)f2bf(v[3]) << 16);
    *reinterpret_cast<uint2*>(p) = o;
}

// C[m,n] = sum_k A[m,k] * B[n,k]  (+bias[n]). A: MxK row-major, B: NxK row-major.
// 64x64 tile, BK=16, 256 threads, 4x4 per thread.
template <typename TA, typename TB, typename TC, bool HAS_BIAS>
__global__ __launch_bounds__(256) void gemm_nt(const TA* __restrict__ A,
                                               const TB* __restrict__ Bm,
                                               const float* __restrict__ bias,
                                               TC* __restrict__ Cm,
                                               int M, int Nn, int K) {
    __shared__ float As[16][64];
    __shared__ float Bs[16][64];
    const int tid = threadIdx.x;
    const int tx = tid & 15, ty = tid >> 4;
    const int m0 = blockIdx.y << 6, n0 = blockIdx.x << 6;
    const int lr = tid >> 2;            // 0..63 (tile row)
    const int lk = (tid & 3) << 2;      // 0,4,8,12 (k offset)
    float acc[4][4] = {};

    const TA* pa = A + (size_t)(m0 + lr) * K + lk;
    const TB* pb = Bm + (size_t)(n0 + lr) * K + lk;

    for (int k0 = 0; k0 < K; k0 += 16) {
        float a4[4], b4[4];
        load4(pa + k0, a4);
        load4(pb + k0, b4);
        __syncthreads();
#pragma unroll
        for (int q = 0; q < 4; ++q) { As[lk + q][lr] = a4[q]; Bs[lk + q][lr] = b4[q]; }
        __syncthreads();
#pragma unroll
        for (int kk = 0; kk < 16; ++kk) {
            float av[4], bv[4];
#pragma unroll
            for (int i = 0; i < 4; ++i) av[i] = As[kk][(ty << 2) + i];
#pragma unroll
            for (int j = 0; j < 4; ++j) bv[j] = Bs[kk][(tx << 2) + j];
#pragma unroll
            for (int i = 0; i < 4; ++i)
#pragma unroll
                for (int j = 0; j < 4; ++j) acc[i][j] += av[i] * bv[j];
        }
    }

    float bv4[4] = {0.f, 0.f, 0.f, 0.f};
    if (HAS_BIAS) {
#pragma unroll
        for (int j = 0; j < 4; ++j) bv4[j] = bias[n0 + (tx << 2) + j];
    }
#pragma unroll
    for (int i = 0; i < 4; ++i) {
        int m = m0 + (ty << 2) + i;
        float o[4];
#pragma unroll
        for (int j = 0; j < 4; ++j) o[j] = acc[i][j] + bv4[j];
        store4(Cm + (size_t)m * Nn + n0 + (tx << 2), o);
    }
}

// Column-wise (over n=0..1023) online softmax stats (max, sumexp) per (b, j).
__global__ __launch_bounds__(256) void colsm_stats(const float* __restrict__ X,
                                                   float* __restrict__ Mo,
                                                   float* __restrict__ So,
                                                   int ncols) {
    const int tid = threadIdx.x, lane = tid & 63, chunk = tid >> 6;
    const int b = blockIdx.y;
    const int j = blockIdx.x * 64 + lane;
    const float* p = X + (size_t)b * SEQ * ncols + j;
    float m = -3.0e38f, s = 0.f;
    const int nEnd = (chunk + 1) << 8;
    for (int n = chunk << 8; n < nEnd; ++n) {
        float v = p[(size_t)n * ncols];
        float nm = fmaxf(m, v);
        s = s * __expf(m - nm) + __expf(v - nm);
        m = nm;
    }
    __shared__ float ms[4][64], ss[4][64];
    ms[chunk][lane] = m; ss[chunk][lane] = s;
    __syncthreads();
    if (tid < 64) {
        float M = fmaxf(fmaxf(ms[0][lane], ms[1][lane]), fmaxf(ms[2][lane], ms[3][lane]));
        float S = ss[0][lane] * __expf(ms[0][lane] - M) + ss[1][lane] * __expf(ms[1][lane] - M) +
                  ss[2][lane] * __expf(ms[2][lane] - M) + ss[3][lane] * __expf(ms[3][lane] - M);
        Mo[b * ncols + j] = M;
        So[b * ncols + j] = S;
    }
}

// kp[b,h,n] = mean_c softmax_n(x)[b,n,h*96+c]
__global__ __launch_bounds__(256) void kp_k(const float* __restrict__ x,
                                            const float* __restrict__ Mx,
                                            const float* __restrict__ Sx,
                                            float* __restrict__ kp) {
    const int n = blockIdx.x, b = blockIdx.y, tid = threadIdx.x;
    __shared__ float p[DIM];
    const float* row = x + ((size_t)b * SEQ + n) * DIM;
#pragma unroll
    for (int q = 0; q < 3; ++q) {
        int j = tid + (q << 8);
        p[j] = __expf(row[j] - Mx[b * DIM + j]) / Sx[b * DIM + j];
    }
    __syncthreads();
    if (tid < NHEAD) {
        float s = 0.f;
        for (int c = 0; c < CHD; ++c) s += p[tid * CHD + c];
        kp[((size_t)b * NHEAD + tid) * SEQ + n] = s * (1.f / (float)CHD);
    }
}

// attn[b,j] = sigmoid( (1/Sq) * sum_n exp(Q[b,n,j]-Mq) * kp[b,h(j),n] ) * temp[h]
__global__ __launch_bounds__(256) void attn_k(const float* __restrict__ Q,
                                              const float* __restrict__ Mq,
                                              const float* __restrict__ Sq,
                                              const float* __restrict__ kp,
                                              const float* __restrict__ temp,
                                              float* __restrict__ attnv) {
    const int tid = threadIdx.x, lane = tid & 63, chunk = tid >> 6;
    const int b = blockIdx.y;
    const int j = blockIdx.x * 64 + lane;
    const int h = j / CHD;
    const float mq = Mq[b * DIM + j];
    const float* qp = Q + (size_t)b * SEQ * DIM + j;
    const float* kpp = kp + ((size_t)b * NHEAD + h) * SEQ;
    float acc = 0.f;
    const int nEnd = (chunk + 1) << 8;
    for (int n = chunk << 8; n < nEnd; ++n)
        acc += __expf(qp[(size_t)n * DIM] - mq) * kpp[n];
    __shared__ float accs[4][64];
    accs[chunk][lane] = acc;
    __syncthreads();
    if (tid < 64) {
        float a = accs[0][lane] + accs[1][lane] + accs[2][lane] + accs[3][lane];
        float z = a / Sq[b * DIM + j];
        attnv[b * DIM + j] = temp[h] / (1.f + __expf(-z));
    }
}

// h2[b,n,ch] = gamma[ch]*(dwconv3x3(h1)[b,n,ch] + dwb[ch]) + h1[b,n,ch]
__global__ __launch_bounds__(256) void dwconv_k(const u16* __restrict__ h1,
                                                const float* __restrict__ w,
                                                const float* __restrict__ dwb,
                                                const float* __restrict__ gamma,
                                                u16* __restrict__ h2) {
    const int ch = (blockIdx.x << 8) + threadIdx.x;
    const int n = blockIdx.y, b = blockIdx.z;
    const int y = n >> 5, xw = n & 31;
    const u16* base = h1 + (size_t)b * SEQ * HID + ch;
    float acc = 0.f;
#pragma unroll
    for (int dy = 0; dy < 3; ++dy) {
        int yy = y + dy - 1;
        if ((unsigned)yy > 31u) continue;
#pragma unroll
        for (int dx = 0; dx < 3; ++dx) {
            int xx = xw + dx - 1;
            if ((unsigned)xx > 31u) continue;
            acc += bf2f(base[(size_t)((yy << 5) + xx) * HID]) * w[ch * 9 + dy * 3 + dx];
        }
    }
    float r = gamma[ch] * (acc + dwb[ch]) + bf2f(base[(size_t)n * HID]);
    h2[((size_t)b * SEQ + n) * HID + ch] = f2bf(r);
}

// LayerNorm(768) then out[b,n,j] = attn[b,j]*v ; out2[b,h,n,c] = same value.
__global__ __launch_bounds__(256) void ln_out_k(const float* __restrict__ vpre,
                                                const float* __restrict__ lnw,
                                                const float* __restrict__ lnb,
                                                const float* __restrict__ attnv,
                                                float* __restrict__ out,
                                                float* __restrict__ out2) {
    const int n = blockIdx.x, b = blockIdx.y, tid = threadIdx.x;
    __shared__ float red[4];
    const float* row = vpre + ((size_t)b * SEQ + n) * DIM;
    float v[3];
    float s = 0.f;
#pragma unroll
    for (int q = 0; q < 3; ++q) { v[q] = row[tid + (q << 8)]; s += v[q]; }
#pragma unroll
    for (int o = 32; o; o >>= 1) s += __shfl_down(s, o, 64);
    if ((tid & 63) == 0) red[tid >> 6] = s;
    __syncthreads();
    const float mu = (red[0] + red[1] + red[2] + red[3]) * (1.f / (float)DIM);
    __syncthreads();
    float vs = 0.f;
#pragma unroll
    for (int q = 0; q < 3; ++q) { float d = v[q] - mu; vs += d * d; }
#pragma unroll
    for (int o = 32; o; o >>= 1) vs += __shfl_down(vs, o, 64);
    if ((tid & 63) == 0) red[tid >> 6] = vs;
    __syncthreads();
    const float rstd = rsqrtf((red[0] + red[1] + red[2] + red[3]) * (1.f / (float)DIM) + 1e-5f);
    const float* at = attnv + b * DIM;
    float* orow = out + ((size_t)b * SEQ + n) * DIM;
#pragma unroll
    for (int q = 0; q < 3; ++q) {
        int j = tid + (q << 8);
        float o = (v[q] - mu) * rstd * lnw[j] + lnb[j];
        o *= at[j];
        orow[j] = o;
        int h = j / CHD, c = j - h * CHD;
        out2[(((size_t)b * NHEAD + h) * SEQ + n) * CHD + c] = o;
    }
}

extern "C" void kernel_launch(void* const* d_in, const int* in_sizes, int n_in,
                              void* d_out, int out_size, void* d_ws, size_t ws_size,
                              hipStream_t stream) {
    const float* x     = (const float*)d_in[0];
    const float* Wq    = (const float*)d_in[1];
    const float* temp  = (const float*)d_in[2];
    const float* fc1w  = (const float*)d_in[3];
    const float* fc1b  = (const float*)d_in[4];
    const float* dww   = (const float*)d_in[5];
    const float* dwb   = (const float*)d_in[6];
    const float* gamma = (const float*)d_in[7];
    const float* fc2w  = (const float*)d_in[8];
    const float* fc2b  = (const float*)d_in[9];
    const float* lnw   = (const float*)d_in[10];
    const float* lnb   = (const float*)d_in[11];

    float* out  = (float*)d_out;
    float* out2 = out + (size_t)BATCH * SEQ * DIM;

    // Workspace layout (bytes):
    //   [0, 50331648)                : Q (fp32, 16384x768)  -- later reused for v_pre
    //   [50331648, 151 - )           : h1 (bf16, 16384x3072) = 100663296 B
    //   then small stats buffers.
    char* ws = (char*)d_ws;
    float* Q   = (float*)ws;
    u16*   h1  = (u16*)(ws + 50331648);
    float* Mx  = (float*)(ws + 50331648 + 100663296);
    float* Sx  = Mx + BATCH * DIM;
    float* Mq  = Sx + BATCH * DIM;
    float* Sq  = Mq + BATCH * DIM;
    float* kp  = Sq + BATCH * DIM;                 // 16*8*1024
    float* attnv = kp + BATCH * NHEAD * SEQ;       // 16*768
    // h2 (bf16, 16384x3072 = 100663296 B) lives in d_out as scratch; it is fully
    // consumed by gemm3 before ln_out_k overwrites d_out.
    u16* h2 = (u16*)d_out;

    // ---- attention path ----
    gemm_nt<float, float, float, false><<<dim3(DIM / 64, MTOT / 64), 256, 0, stream>>>(
        x, Wq, nullptr, Q, MTOT, DIM, DIM);
    colsm_stats<<<dim3(DIM / 64, BATCH), 256, 0, stream>>>(x, Mx, Sx, DIM);
    colsm_stats<<<dim3(DIM / 64, BATCH), 256, 0, stream>>>(Q, Mq, Sq, DIM);
    kp_k<<<dim3(SEQ, BATCH), 256, 0, stream>>>(x, Mx, Sx, kp);
    attn_k<<<dim3(DIM / 64, BATCH), 256, 0, stream>>>(Q, Mq, Sq, kp, temp, attnv);

    // ---- MLP path ----
    gemm_nt<float, float, u16, true><<<dim3(HID / 64, MTOT / 64), 256, 0, stream>>>(
        x, fc1w, fc1b, h1, MTOT, HID, DIM);
    dwconv_k<<<dim3(HID / 256, SEQ, BATCH), 256, 0, stream>>>(h1, dww, dwb, gamma, h2);
    gemm_nt<u16, float, float, true><<<dim3(DIM / 64, MTOT / 64), 256, 0, stream>>>(
        h2, fc2w, fc2b, Q, MTOT, DIM, HID);  // v_pre into Q buffer
    ln_out_k<<<dim3(SEQ, BATCH), 256, 0, stream>>>(Q, lnw, lnb, attnv, out, out2);
}

// Round 2
// 799.994 us; speedup vs baseline: 3.6775x; 3.6775x over previous
//
#include <hip/hip_runtime.h>

// B=16, N=1024 (=32x32), DIM=768, HEADS=8, CH=96, HIDDEN=3072.
#define BATCH 16
#define SEQ   1024
#define DIM   768
#define NHEAD 8
#define CHD   96
#define HID   3072
#define MTOT  (BATCH * SEQ)   // 16384

using u16 = unsigned short;
typedef __attribute__((ext_vector_type(8))) short bf16x8;   // 8 bf16 = 4 VGPRs
typedef __attribute__((ext_vector_type(4))) float f32x4;

#define AS1 __attribute__((address_space(1)))
#define AS3 __attribute__((address_space(3)))

__device__ inline float bf2f(u16 u) {
    union { unsigned int i; float f; } v; v.i = ((unsigned int)u) << 16; return v.f;
}
__device__ inline u16 f2bf(float f) {
    union { float f; unsigned int i; } v; v.f = f;
    unsigned int r = v.i + 0x7FFFu + ((v.i >> 16) & 1u);
    return (u16)(r >> 16);
}

__device__ inline void gld16(const void* g, void* l) {
    __builtin_amdgcn_global_load_lds((AS1 const void*)g, (AS3 void*)l, 16, 0, 0);
}

__device__ inline void storeC(float* p, float v) { *p = v; }
__device__ inline void storeC(u16* p, float v) { *p = f2bf(v); }

// ---------------------------------------------------------------------------
// m97-structure bf16 MFMA GEMM: C[m,n] = sum_k A[m,k]*B[n,k] (+bias[n]).
// A: MxK bf16 row-major, B: NxK bf16 row-major (i.e. weight W[n][k]).
// 128x128 tile, BK=32, 256 threads (4 waves, 2x2 of 64x64), 16x16x32 MFMA.
// ---------------------------------------------------------------------------
template <bool HAS_BIAS, typename TC>
__global__ __launch_bounds__(256) void gemm_mfma(const u16* __restrict__ A,
                                                 const u16* __restrict__ B,
                                                 const float* __restrict__ bias,
                                                 TC* __restrict__ C,
                                                 int M, int N, int K) {
    __shared__ u16 As[128 * 32];   // [row][k] row-major, 8 KB
    __shared__ u16 Bs[128 * 32];
    const int tid = threadIdx.x;
    const int lane = tid & 63;
    const int m0 = blockIdx.y << 7, n0 = blockIdx.x << 7;
    const int wave = tid >> 6;
    const int wm = (wave >> 1) << 6, wn = (wave & 1) << 6;

    f32x4 acc[4][4] = {};

    // Staging: chunk idx = c*256 + tid; row = idx>>2 (0..127), kc = idx&3.
    // LDS dest = base + idx*16B (linear => HW's wave-uniform-base + lane*16 holds).
    const int row0 = tid >> 2;
    const int kc8 = (tid & 3) << 3;
    const u16* pa0 = A + (size_t)(m0 + row0) * K + kc8;
    const u16* pa1 = A + (size_t)(m0 + 64 + row0) * K + kc8;
    const u16* pb0 = B + (size_t)(n0 + row0) * K + kc8;
    const u16* pb1 = B + (size_t)(n0 + 64 + row0) * K + kc8;
    u16* da0 = &As[tid * 8];
    u16* da1 = &As[(256 + tid) * 8];
    u16* db0 = &Bs[tid * 8];
    u16* db1 = &Bs[(256 + tid) * 8];

    const int lrow = lane & 15;
    const int kgrp = (lane >> 4) << 3;

    for (int k0 = 0; k0 < K; k0 += 32) {
        gld16(pa0 + k0, da0);
        gld16(pa1 + k0, da1);
        gld16(pb0 + k0, db0);
        gld16(pb1 + k0, db1);
        __syncthreads();   // drains vmcnt -> LDS tile ready

        bf16x8 af[4], bfr[4];
#pragma unroll
        for (int i = 0; i < 4; ++i)
            af[i] = *(const bf16x8*)&As[(wm + i * 16 + lrow) * 32 + kgrp];
#pragma unroll
        for (int j = 0; j < 4; ++j)
            bfr[j] = *(const bf16x8*)&Bs[(wn + j * 16 + lrow) * 32 + kgrp];
#pragma unroll
        for (int i = 0; i < 4; ++i)
#pragma unroll
            for (int j = 0; j < 4; ++j)
                acc[i][j] = __builtin_amdgcn_mfma_f32_16x16x32_bf16(af[i], bfr[j], acc[i][j], 0, 0, 0);
        __syncthreads();   // protect LDS before next overwrite
    }

    // C/D layout: col = lane&15, row = (lane>>4)*4 + reg  [m89/m91 verified]
    const int crow = (lane >> 4) << 2;
    const int ccol = lane & 15;
#pragma unroll
    for (int i = 0; i < 4; ++i) {
        const int gm = m0 + wm + i * 16 + crow;
#pragma unroll
        for (int j = 0; j < 4; ++j) {
            const int gn = n0 + wn + j * 16 + ccol;
            const float bv = HAS_BIAS ? bias[gn] : 0.f;
#pragma unroll
            for (int r = 0; r < 4; ++r)
                storeC(C + (size_t)(gm + r) * N + gn, acc[i][j][r] + bv);
        }
    }
}

// fp32 -> bf16 bulk convert (4 elems/thread)
__global__ __launch_bounds__(256) void cvt_f2bf(const float* __restrict__ in,
                                                u16* __restrict__ out, int n4) {
    int i = blockIdx.x * 256 + threadIdx.x;
    if (i >= n4) return;
    float4 v = reinterpret_cast<const float4*>(in)[i];
    ushort4 o;
    o.x = f2bf(v.x); o.y = f2bf(v.y); o.z = f2bf(v.z); o.w = f2bf(v.w);
    reinterpret_cast<ushort4*>(out)[i] = o;
}

// Column-wise (over n=0..1023) online softmax stats (max, sumexp) per (b, j).
template <typename T>
__global__ __launch_bounds__(256) void colsm_stats(const T* __restrict__ X,
                                                   float* __restrict__ Mo,
                                                   float* __restrict__ So,
                                                   int ncols) {
    const int tid = threadIdx.x, lane = tid & 63, chunk = tid >> 6;
    const int b = blockIdx.y;
    const int j = blockIdx.x * 64 + lane;
    const T* p = X + (size_t)b * SEQ * ncols + j;
    float m = -3.0e38f, s = 0.f;
    const int nEnd = (chunk + 1) << 8;
    for (int n = chunk << 8; n < nEnd; ++n) {
        float raw;
        if constexpr (sizeof(T) == 2) raw = bf2f(p[(size_t)n * ncols]);
        else raw = p[(size_t)n * ncols];
        float nm = fmaxf(m, raw);
        s = s * __expf(m - nm) + __expf(raw - nm);
        m = nm;
    }
    __shared__ float ms[4][64], ss[4][64];
    ms[chunk][lane] = m; ss[chunk][lane] = s;
    __syncthreads();
    if (tid < 64) {
        float M = fmaxf(fmaxf(ms[0][lane], ms[1][lane]), fmaxf(ms[2][lane], ms[3][lane]));
        float S = ss[0][lane] * __expf(ms[0][lane] - M) + ss[1][lane] * __expf(ms[1][lane] - M) +
                  ss[2][lane] * __expf(ms[2][lane] - M) + ss[3][lane] * __expf(ms[3][lane] - M);
        Mo[b * ncols + j] = M;
        So[b * ncols + j] = S;
    }
}

// kp[b,h,n] = mean_c softmax_n(x)[b,n,h*96+c]
__global__ __launch_bounds__(256) void kp_k(const float* __restrict__ x,
                                            const float* __restrict__ Mx,
                                            const float* __restrict__ Sx,
                                            float* __restrict__ kp) {
    const int n = blockIdx.x, b = blockIdx.y, tid = threadIdx.x;
    __shared__ float p[DIM];
    const float* row = x + ((size_t)b * SEQ + n) * DIM;
#pragma unroll
    for (int q = 0; q < 3; ++q) {
        int j = tid + (q << 8);
        p[j] = __expf(row[j] - Mx[b * DIM + j]) / Sx[b * DIM + j];
    }
    __syncthreads();
    if (tid < NHEAD) {
        float s = 0.f;
        for (int c = 0; c < CHD; ++c) s += p[tid * CHD + c];
        kp[((size_t)b * NHEAD + tid) * SEQ + n] = s * (1.f / (float)CHD);
    }
}

// attn[b,j] = sigmoid( (1/Sq) * sum_n exp(Q[b,n,j]-Mq) * kp[b,h(j),n] ) * temp[h]
__global__ __launch_bounds__(256) void attn_k(const u16* __restrict__ Q,
                                              const float* __restrict__ Mq,
                                              const float* __restrict__ Sq,
                                              const float* __restrict__ kp,
                                              const float* __restrict__ temp,
                                              float* __restrict__ attnv) {
    const int tid = threadIdx.x, lane = tid & 63, chunk = tid >> 6;
    const int b = blockIdx.y;
    const int j = blockIdx.x * 64 + lane;
    const int h = j / CHD;
    const float mq = Mq[b * DIM + j];
    const u16* qp = Q + (size_t)b * SEQ * DIM + j;
    const float* kpp = kp + ((size_t)b * NHEAD + h) * SEQ;
    float acc = 0.f;
    const int nEnd = (chunk + 1) << 8;
    for (int n = chunk << 8; n < nEnd; ++n)
        acc += __expf(bf2f(qp[(size_t)n * DIM]) - mq) * kpp[n];
    __shared__ float accs[4][64];
    accs[chunk][lane] = acc;
    __syncthreads();
    if (tid < 64) {
        float a = accs[0][lane] + accs[1][lane] + accs[2][lane] + accs[3][lane];
        float z = a / Sq[b * DIM + j];
        attnv[b * DIM + j] = temp[h] / (1.f + __expf(-z));
    }
}

// h2[b,n,ch] = gamma[ch]*(dwconv3x3(h1)[b,n,ch] + dwb[ch]) + h1[b,n,ch]
__global__ __launch_bounds__(256) void dwconv_k(const u16* __restrict__ h1,
                                                const float* __restrict__ w,
                                                const float* __restrict__ dwb,
                                                const float* __restrict__ gamma,
                                                u16* __restrict__ h2) {
    const int ch = (blockIdx.x << 8) + threadIdx.x;
    const int n = blockIdx.y, b = blockIdx.z;
    const int y = n >> 5, xw = n & 31;
    const u16* base = h1 + (size_t)b * SEQ * HID + ch;
    float acc = 0.f;
#pragma unroll
    for (int dy = 0; dy < 3; ++dy) {
        int yy = y + dy - 1;
        if ((unsigned)yy > 31u) continue;
#pragma unroll
        for (int dx = 0; dx < 3; ++dx) {
            int xx = xw + dx - 1;
            if ((unsigned)xx > 31u) continue;
            acc += bf2f(base[(size_t)((yy << 5) + xx) * HID]) * w[ch * 9 + dy * 3 + dx];
        }
    }
    float r = gamma[ch] * (acc + dwb[ch]) + bf2f(base[(size_t)n * HID]);
    h2[((size_t)b * SEQ + n) * HID + ch] = f2bf(r);
}

// LayerNorm(768) then out[b,n,j] = attn[b,j]*v ; out2[b,h,n,c] = same value.
__global__ __launch_bounds__(256) void ln_out_k(const u16* __restrict__ vpre,
                                                const float* __restrict__ lnw,
                                                const float* __restrict__ lnb,
                                                const float* __restrict__ attnv,
                                                float* __restrict__ out,
                                                float* __restrict__ out2) {
    const int n = blockIdx.x, b = blockIdx.y, tid = threadIdx.x;
    __shared__ float red[4];
    const u16* row = vpre + ((size_t)b * SEQ + n) * DIM;
    float v[3];
    float s = 0.f;
#pragma unroll
    for (int q = 0; q < 3; ++q) { v[q] = bf2f(row[tid + (q << 8)]); s += v[q]; }
#pragma unroll
    for (int o = 32; o; o >>= 1) s += __shfl_down(s, o, 64);
    if ((tid & 63) == 0) red[tid >> 6] = s;
    __syncthreads();
    const float mu = (red[0] + red[1] + red[2] + red[3]) * (1.f / (float)DIM);
    __syncthreads();
    float vs = 0.f;
#pragma unroll
    for (int q = 0; q < 3; ++q) { float d = v[q] - mu; vs += d * d; }
#pragma unroll
    for (int o = 32; o; o >>= 1) vs += __shfl_down(vs, o, 64);
    if ((tid & 63) == 0) red[tid >> 6] = vs;
    __syncthreads();
    const float rstd = rsqrtf((red[0] + red[1] + red[2] + red[3]) * (1.f / (float)DIM) + 1e-5f);
    const float* at = attnv + b * DIM;
    float* orow = out + ((size_t)b * SEQ + n) * DIM;
#pragma unroll
    for (int q = 0; q < 3; ++q) {
        int j = tid + (q << 8);
        float o = (v[q] - mu) * rstd * lnw[j] + lnb[j];
        o *= at[j];
        orow[j] = o;
        int h = j / CHD, c = j - h * CHD;
        out2[(((size_t)b * NHEAD + h) * SEQ + n) * CHD + c] = o;
    }
}

extern "C" void kernel_launch(void* const* d_in, const int* in_sizes, int n_in,
                              void* d_out, int out_size, void* d_ws, size_t ws_size,
                              hipStream_t stream) {
    const float* x     = (const float*)d_in[0];
    const float* Wq    = (const float*)d_in[1];
    const float* temp  = (const float*)d_in[2];
    const float* fc1w  = (const float*)d_in[3];
    const float* fc1b  = (const float*)d_in[4];
    const float* dww   = (const float*)d_in[5];
    const float* dwb   = (const float*)d_in[6];
    const float* gamma = (const float*)d_in[7];
    const float* fc2w  = (const float*)d_in[8];
    const float* fc2b  = (const float*)d_in[9];
    const float* lnw   = (const float*)d_in[10];
    const float* lnb   = (const float*)d_in[11];

    float* out  = (float*)d_out;
    float* out2 = out + (size_t)BATCH * SEQ * DIM;

    // Workspace layout (bytes):
    //   xb    : [0, 25165824)            bf16 x              (reused as vpre_b by fc2)
    //   h1    : [25165824, +100663296)   bf16 fc1 out
    //   Wqb   : [125829120, +1179648)
    //   fc1wb : [127008768, +4718592)
    //   fc2wb : [131727360, +4718592)
    //   stats : [136445952, ...)         ~770 KB
    // total ~137.2 MB (< round-0-proven 152 MB).
    char* ws = (char*)d_ws;
    u16* xb     = (u16*)ws;
    u16* h1     = (u16*)(ws + 25165824);
    u16* Wqb    = (u16*)(ws + 125829120);
    u16* fc1wb  = (u16*)(ws + 127008768);
    u16* fc2wb  = (u16*)(ws + 131727360);
    float* Mx   = (float*)(ws + 136445952);
    float* Sx   = Mx + BATCH * DIM;
    float* Mq   = Sx + BATCH * DIM;
    float* Sq   = Mq + BATCH * DIM;
    float* kp   = Sq + BATCH * DIM;            // 16*8*1024
    float* attnv = kp + BATCH * NHEAD * SEQ;   // 16*768
    u16* vpreb  = xb;                          // reuse after fc1 gemm consumed xb

    // Qb (bf16 16384x768 = 25.2 MB) lives at the start of d_out until attn_k
    // consumes it; then dwconv overwrites d_out with h2 (bf16 16384x3072 =
    // 100.66 MB = full d_out); fc2 consumes h2 before ln_out writes out/out2.
    u16* Qb = (u16*)d_out;
    u16* h2 = (u16*)d_out;

    // ---- fp32 -> bf16 conversions ----
    cvt_f2bf<<<(MTOT * DIM / 4 + 255) / 256, 256, 0, stream>>>(x, xb, MTOT * DIM / 4);
    cvt_f2bf<<<(DIM * DIM / 4 + 255) / 256, 256, 0, stream>>>(Wq, Wqb, DIM * DIM / 4);
    cvt_f2bf<<<(HID * DIM / 4 + 255) / 256, 256, 0, stream>>>(fc1w, fc1wb, HID * DIM / 4);
    cvt_f2bf<<<(DIM * HID / 4 + 255) / 256, 256, 0, stream>>>(fc2w, fc2wb, DIM * HID / 4);

    // ---- attention path ----
    gemm_mfma<false, u16><<<dim3(DIM / 128, MTOT / 128), 256, 0, stream>>>(
        xb, Wqb, nullptr, Qb, MTOT, DIM, DIM);
    colsm_stats<float><<<dim3(DIM / 64, BATCH), 256, 0, stream>>>(x, Mx, Sx, DIM);
    colsm_stats<u16><<<dim3(DIM / 64, BATCH), 256, 0, stream>>>(Qb, Mq, Sq, DIM);
    kp_k<<<dim3(SEQ, BATCH), 256, 0, stream>>>(x, Mx, Sx, kp);
    attn_k<<<dim3(DIM / 64, BATCH), 256, 0, stream>>>(Qb, Mq, Sq, kp, temp, attnv);

    // ---- MLP path ----
    gemm_mfma<true, u16><<<dim3(HID / 128, MTOT / 128), 256, 0, stream>>>(
        xb, fc1wb, fc1b, h1, MTOT, HID, DIM);
    dwconv_k<<<dim3(HID / 256, SEQ, BATCH), 256, 0, stream>>>(h1, dww, dwb, gamma, h2);
    gemm_mfma<true, u16><<<dim3(DIM / 128, MTOT / 128), 256, 0, stream>>>(
        h2, fc2wb, fc2b, vpreb, MTOT, DIM, HID);
    ln_out_k<<<dim3(SEQ, BATCH), 256, 0, stream>>>(vpreb, lnw, lnb, attnv, out, out2);
}

// Round 3
// 464.440 us; speedup vs baseline: 6.3345x; 1.7225x over previous
//
#include <hip/hip_runtime.h>

// B=16, N=1024 (=32x32), DIM=768, HEADS=8, CH=96, HIDDEN=3072.
#define BATCH 16
#define SEQ   1024
#define DIM   768
#define NHEAD 8
#define CHD   96
#define HID   3072
#define MTOT  (BATCH * SEQ)   // 16384

using u16 = unsigned short;
typedef __attribute__((ext_vector_type(8))) short bf16x8;   // 8 bf16 = 4 VGPRs
typedef __attribute__((ext_vector_type(4))) float f32x4;

#define AS1 __attribute__((address_space(1)))
#define AS3 __attribute__((address_space(3)))

__device__ inline float bf2f(u16 u) {
    union { unsigned int i; float f; } v; v.i = ((unsigned int)u) << 16; return v.f;
}
__device__ inline u16 f2bf(float f) {
    union { float f; unsigned int i; } v; v.f = f;
    unsigned int r = v.i + 0x7FFFu + ((v.i >> 16) & 1u);
    return (u16)(r >> 16);
}

__device__ inline void gld16(const void* g, void* l) {
    __builtin_amdgcn_global_load_lds((AS1 const void*)g, (AS3 void*)l, 16, 0, 0);
}

__device__ inline void storeC(float* p, float v) { *p = v; }
__device__ inline void storeC(u16* p, float v) { *p = f2bf(v); }

// ---------------------------------------------------------------------------
// m97-structure bf16 MFMA GEMM: C[m,n] = sum_k A[m,k]*B[n,k] (+bias[n]).
// A: MxK bf16 row-major, B: NxK bf16 row-major (i.e. weight W[n][k]).
// 128x128 tile, BK=32, 256 threads (4 waves, 2x2 of 64x64), 16x16x32 MFMA.
// ---------------------------------------------------------------------------
template <bool HAS_BIAS, typename TC>
__global__ __launch_bounds__(256) void gemm_mfma(const u16* __restrict__ A,
                                                 const u16* __restrict__ B,
                                                 const float* __restrict__ bias,
                                                 TC* __restrict__ C,
                                                 int M, int N, int K) {
    __shared__ u16 As[128 * 32];   // [row][k] row-major, 8 KB
    __shared__ u16 Bs[128 * 32];
    const int tid = threadIdx.x;
    const int lane = tid & 63;
    const int m0 = blockIdx.y << 7, n0 = blockIdx.x << 7;
    const int wave = tid >> 6;
    const int wm = (wave >> 1) << 6, wn = (wave & 1) << 6;

    f32x4 acc[4][4] = {};

    const int row0 = tid >> 2;
    const int kc8 = (tid & 3) << 3;
    const u16* pa0 = A + (size_t)(m0 + row0) * K + kc8;
    const u16* pa1 = A + (size_t)(m0 + 64 + row0) * K + kc8;
    const u16* pb0 = B + (size_t)(n0 + row0) * K + kc8;
    const u16* pb1 = B + (size_t)(n0 + 64 + row0) * K + kc8;
    u16* da0 = &As[tid * 8];
    u16* da1 = &As[(256 + tid) * 8];
    u16* db0 = &Bs[tid * 8];
    u16* db1 = &Bs[(256 + tid) * 8];

    const int lrow = lane & 15;
    const int kgrp = (lane >> 4) << 3;

    for (int k0 = 0; k0 < K; k0 += 32) {
        gld16(pa0 + k0, da0);
        gld16(pa1 + k0, da1);
        gld16(pb0 + k0, db0);
        gld16(pb1 + k0, db1);
        __syncthreads();   // drains vmcnt -> LDS tile ready

        bf16x8 af[4], bfr[4];
#pragma unroll
        for (int i = 0; i < 4; ++i)
            af[i] = *(const bf16x8*)&As[(wm + i * 16 + lrow) * 32 + kgrp];
#pragma unroll
        for (int j = 0; j < 4; ++j)
            bfr[j] = *(const bf16x8*)&Bs[(wn + j * 16 + lrow) * 32 + kgrp];
#pragma unroll
        for (int i = 0; i < 4; ++i)
#pragma unroll
            for (int j = 0; j < 4; ++j)
                acc[i][j] = __builtin_amdgcn_mfma_f32_16x16x32_bf16(af[i], bfr[j], acc[i][j], 0, 0, 0);
        __syncthreads();   // protect LDS before next overwrite
    }

    // C/D layout: col = lane&15, row = (lane>>4)*4 + reg  [m89/m91 verified]
    const int crow = (lane >> 4) << 2;
    const int ccol = lane & 15;
#pragma unroll
    for (int i = 0; i < 4; ++i) {
        const int gm = m0 + wm + i * 16 + crow;
#pragma unroll
        for (int j = 0; j < 4; ++j) {
            const int gn = n0 + wn + j * 16 + ccol;
            const float bv = HAS_BIAS ? bias[gn] : 0.f;
#pragma unroll
            for (int r = 0; r < 4; ++r)
                storeC(C + (size_t)(gm + r) * N + gn, acc[i][j][r] + bv);
        }
    }
}

// fp32 -> bf16 bulk convert (4 elems/thread)
__global__ __launch_bounds__(256) void cvt_f2bf(const float* __restrict__ in,
                                                u16* __restrict__ out, int n4) {
    int i = blockIdx.x * 256 + threadIdx.x;
    if (i >= n4) return;
    float4 v = reinterpret_cast<const float4*>(in)[i];
    ushort4 o;
    o.x = f2bf(v.x); o.y = f2bf(v.y); o.z = f2bf(v.z); o.w = f2bf(v.w);
    reinterpret_cast<ushort4*>(out)[i] = o;
}

// Column-wise (over n=0..1023) online softmax stats (max, sumexp) per (b, j).
template <typename T>
__global__ __launch_bounds__(256) void colsm_stats(const T* __restrict__ X,
                                                   float* __restrict__ Mo,
                                                   float* __restrict__ So,
                                                   int ncols) {
    const int tid = threadIdx.x, lane = tid & 63, chunk = tid >> 6;
    const int b = blockIdx.y;
    const int j = blockIdx.x * 64 + lane;
    const T* p = X + (size_t)b * SEQ * ncols + j;
    float m = -3.0e38f, s = 0.f;
    const int nEnd = (chunk + 1) << 8;
    for (int n = chunk << 8; n < nEnd; ++n) {
        float raw;
        if constexpr (sizeof(T) == 2) raw = bf2f(p[(size_t)n * ncols]);
        else raw = p[(size_t)n * ncols];
        float nm = fmaxf(m, raw);
        s = s * __expf(m - nm) + __expf(raw - nm);
        m = nm;
    }
    __shared__ float ms[4][64], ss[4][64];
    ms[chunk][lane] = m; ss[chunk][lane] = s;
    __syncthreads();
    if (tid < 64) {
        float M = fmaxf(fmaxf(ms[0][lane], ms[1][lane]), fmaxf(ms[2][lane], ms[3][lane]));
        float S = ss[0][lane] * __expf(ms[0][lane] - M) + ss[1][lane] * __expf(ms[1][lane] - M) +
                  ss[2][lane] * __expf(ms[2][lane] - M) + ss[3][lane] * __expf(ms[3][lane] - M);
        Mo[b * ncols + j] = M;
        So[b * ncols + j] = S;
    }
}

// kp[b,h,n] = mean_c softmax_n(x)[b,n,h*96+c]
__global__ __launch_bounds__(256) void kp_k(const float* __restrict__ x,
                                            const float* __restrict__ Mx,
                                            const float* __restrict__ Sx,
                                            float* __restrict__ kp) {
    const int n = blockIdx.x, b = blockIdx.y, tid = threadIdx.x;
    __shared__ float p[DIM];
    const float* row = x + ((size_t)b * SEQ + n) * DIM;
#pragma unroll
    for (int q = 0; q < 3; ++q) {
        int j = tid + (q << 8);
        p[j] = __expf(row[j] - Mx[b * DIM + j]) / Sx[b * DIM + j];
    }
    __syncthreads();
    if (tid < NHEAD) {
        float s = 0.f;
        for (int c = 0; c < CHD; ++c) s += p[tid * CHD + c];
        kp[((size_t)b * NHEAD + tid) * SEQ + n] = s * (1.f / (float)CHD);
    }
}

// attn[b,j] = sigmoid( (1/Sq) * sum_n exp(Q[b,n,j]-Mq) * kp[b,h(j),n] ) * temp[h]
__global__ __launch_bounds__(256) void attn_k(const u16* __restrict__ Q,
                                              const float* __restrict__ Mq,
                                              const float* __restrict__ Sq,
                                              const float* __restrict__ kp,
                                              const float* __restrict__ temp,
                                              float* __restrict__ attnv) {
    const int tid = threadIdx.x, lane = tid & 63, chunk = tid >> 6;
    const int b = blockIdx.y;
    const int j = blockIdx.x * 64 + lane;
    const int h = j / CHD;
    const float mq = Mq[b * DIM + j];
    const u16* qp = Q + (size_t)b * SEQ * DIM + j;
    const float* kpp = kp + ((size_t)b * NHEAD + h) * SEQ;
    float acc = 0.f;
    const int nEnd = (chunk + 1) << 8;
    for (int n = chunk << 8; n < nEnd; ++n)
        acc += __expf(bf2f(qp[(size_t)n * DIM]) - mq) * kpp[n];
    __shared__ float accs[4][64];
    accs[chunk][lane] = acc;
    __syncthreads();
    if (tid < 64) {
        float a = accs[0][lane] + accs[1][lane] + accs[2][lane] + accs[3][lane];
        float z = a / Sq[b * DIM + j];
        attnv[b * DIM + j] = temp[h] / (1.f + __expf(-z));
    }
}

// Depthwise 3x3 + residual + gamma, vectorized: each thread owns 8 channels
// (16B loads) x 8 consecutive x-positions. Residual/bias folded into weights:
//   out = conv(h1; gamma*w, center+=1) + gamma*dwb
__global__ __launch_bounds__(128) void dwconv_v(const u16* __restrict__ h1,
                                                const float* __restrict__ w,
                                                const float* __restrict__ dwb,
                                                const float* __restrict__ gamma,
                                                u16* __restrict__ h2) {
    const int g = blockIdx.x * 128 + threadIdx.x;   // ch8 group, 0..383
    const int y = blockIdx.y >> 2;                  // 0..31
    const int xw0 = (blockIdx.y & 3) << 3;          // 0,8,16,24
    const int b = blockIdx.z;
    const int ch0 = g << 3;

    float wreg[8][9], bias2[8];
#pragma unroll
    for (int c = 0; c < 8; ++c) {
        const float gm = gamma[ch0 + c];
#pragma unroll
        for (int k = 0; k < 9; ++k) wreg[c][k] = gm * w[(ch0 + c) * 9 + k];
        wreg[c][4] += 1.0f;                 // residual fold (center tap)
        bias2[c] = gm * dwb[ch0 + c];
    }

    float acc[8][8];
#pragma unroll
    for (int xo = 0; xo < 8; ++xo)
#pragma unroll
        for (int c = 0; c < 8; ++c) acc[xo][c] = bias2[c];

    const u16* base = h1 + (size_t)b * SEQ * HID + ch0;
#pragma unroll
    for (int dy = 0; dy < 3; ++dy) {
        const int yy = y + dy - 1;
        if ((unsigned)yy > 31u) continue;           // wave-uniform
#pragma unroll
        for (int cr = -1; cr <= 8; ++cr) {          // column rel to xw0
            const int col = xw0 + cr;
            if ((unsigned)col > 31u) continue;      // wave-uniform
            const uint4 v = *reinterpret_cast<const uint4*>(
                base + (size_t)((yy << 5) + col) * HID);
            float f[8];
            f[0] = bf2f((u16)(v.x & 0xffff)); f[1] = bf2f((u16)(v.x >> 16));
            f[2] = bf2f((u16)(v.y & 0xffff)); f[3] = bf2f((u16)(v.y >> 16));
            f[4] = bf2f((u16)(v.z & 0xffff)); f[5] = bf2f((u16)(v.w & 0xffff) * 0 + (u16)(v.z >> 16));
            f[6] = bf2f((u16)(v.w & 0xffff)); f[7] = bf2f((u16)(v.w >> 16));
            const int xlo = cr > 0 ? cr - 1 : 0;
            const int xhi = cr < 7 ? cr + 1 : 7;
#pragma unroll
            for (int xo = 0; xo < 8; ++xo) {
                if (xo < xlo || xo > xhi) continue; // compile-time after unroll
                const int dx = cr - xo + 1;
#pragma unroll
                for (int c = 0; c < 8; ++c)
                    acc[xo][c] += f[c] * wreg[c][dy * 3 + dx];
            }
        }
    }

#pragma unroll
    for (int xo = 0; xo < 8; ++xo) {
        const int n = (y << 5) + xw0 + xo;
        uint4 o;
        o.x = (unsigned)f2bf(acc[xo][0]) | ((unsigned)f2bf(acc[xo][1]) << 16);
        o.y = (unsigned)f2bf(acc[xo][2]) | ((unsigned)f2bf(acc[xo][3]) << 16);
        o.z = (unsigned)f2bf(acc[xo][4]) | ((unsigned)f2bf(acc[xo][5]) << 16);
        o.w = (unsigned)f2bf(acc[xo][6]) | ((unsigned)f2bf(acc[xo][7]) << 16);
        *reinterpret_cast<uint4*>(h2 + ((size_t)b * SEQ + n) * HID + ch0) = o;
    }
}

// LayerNorm(768) then out[b,n,j] = attn[b,j]*v ; out2[b,h,n,c] = same value.
__global__ __launch_bounds__(256) void ln_out_k(const u16* __restrict__ vpre,
                                                const float* __restrict__ lnw,
                                                const float* __restrict__ lnb,
                                                const float* __restrict__ attnv,
                                                float* __restrict__ out,
                                                float* __restrict__ out2) {
    const int n = blockIdx.x, b = blockIdx.y, tid = threadIdx.x;
    __shared__ float red[4];
    const u16* row = vpre + ((size_t)b * SEQ + n) * DIM;
    float v[3];
    float s = 0.f;
#pragma unroll
    for (int q = 0; q < 3; ++q) { v[q] = bf2f(row[tid + (q << 8)]); s += v[q]; }
#pragma unroll
    for (int o = 32; o; o >>= 1) s += __shfl_down(s, o, 64);
    if ((tid & 63) == 0) red[tid >> 6] = s;
    __syncthreads();
    const float mu = (red[0] + red[1] + red[2] + red[3]) * (1.f / (float)DIM);
    __syncthreads();
    float vs = 0.f;
#pragma unroll
    for (int q = 0; q < 3; ++q) { float d = v[q] - mu; vs += d * d; }
#pragma unroll
    for (int o = 32; o; o >>= 1) vs += __shfl_down(vs, o, 64);
    if ((tid & 63) == 0) red[tid >> 6] = vs;
    __syncthreads();
    const float rstd = rsqrtf((red[0] + red[1] + red[2] + red[3]) * (1.f / (float)DIM) + 1e-5f);
    const float* at = attnv + b * DIM;
    float* orow = out + ((size_t)b * SEQ + n) * DIM;
#pragma unroll
    for (int q = 0; q < 3; ++q) {
        int j = tid + (q << 8);
        float o = (v[q] - mu) * rstd * lnw[j] + lnb[j];
        o *= at[j];
        orow[j] = o;
        int h = j / CHD, c = j - h * CHD;
        out2[(((size_t)b * NHEAD + h) * SEQ + n) * CHD + c] = o;
    }
}

extern "C" void kernel_launch(void* const* d_in, const int* in_sizes, int n_in,
                              void* d_out, int out_size, void* d_ws, size_t ws_size,
                              hipStream_t stream) {
    const float* x     = (const float*)d_in[0];
    const float* Wq    = (const float*)d_in[1];
    const float* temp  = (const float*)d_in[2];
    const float* fc1w  = (const float*)d_in[3];
    const float* fc1b  = (const float*)d_in[4];
    const float* dww   = (const float*)d_in[5];
    const float* dwb   = (const float*)d_in[6];
    const float* gamma = (const float*)d_in[7];
    const float* fc2w  = (const float*)d_in[8];
    const float* fc2b  = (const float*)d_in[9];
    const float* lnw   = (const float*)d_in[10];
    const float* lnb   = (const float*)d_in[11];

    float* out  = (float*)d_out;
    float* out2 = out + (size_t)BATCH * SEQ * DIM;

    char* ws = (char*)d_ws;
    u16* xb     = (u16*)ws;
    u16* h1     = (u16*)(ws + 25165824);
    u16* Wqb    = (u16*)(ws + 125829120);
    u16* fc1wb  = (u16*)(ws + 127008768);
    u16* fc2wb  = (u16*)(ws + 131727360);
    float* Mx   = (float*)(ws + 136445952);
    float* Sx   = Mx + BATCH * DIM;
    float* Mq   = Sx + BATCH * DIM;
    float* Sq   = Mq + BATCH * DIM;
    float* kp   = Sq + BATCH * DIM;            // 16*8*1024
    float* attnv = kp + BATCH * NHEAD * SEQ;   // 16*768
    u16* vpreb  = xb;                          // reuse after fc1 gemm consumed xb

    // Qb lives in d_out until attn_k consumes it; then dwconv overwrites d_out
    // with h2; fc2 consumes h2 before ln_out writes out/out2.
    u16* Qb = (u16*)d_out;
    u16* h2 = (u16*)d_out;

    // ---- fp32 -> bf16 conversions ----
    cvt_f2bf<<<(MTOT * DIM / 4 + 255) / 256, 256, 0, stream>>>(x, xb, MTOT * DIM / 4);
    cvt_f2bf<<<(DIM * DIM / 4 + 255) / 256, 256, 0, stream>>>(Wq, Wqb, DIM * DIM / 4);
    cvt_f2bf<<<(HID * DIM / 4 + 255) / 256, 256, 0, stream>>>(fc1w, fc1wb, HID * DIM / 4);
    cvt_f2bf<<<(DIM * HID / 4 + 255) / 256, 256, 0, stream>>>(fc2w, fc2wb, DIM * HID / 4);

    // ---- attention path ----
    gemm_mfma<false, u16><<<dim3(DIM / 128, MTOT / 128), 256, 0, stream>>>(
        xb, Wqb, nullptr, Qb, MTOT, DIM, DIM);
    colsm_stats<float><<<dim3(DIM / 64, BATCH), 256, 0, stream>>>(x, Mx, Sx, DIM);
    colsm_stats<u16><<<dim3(DIM / 64, BATCH), 256, 0, stream>>>(Qb, Mq, Sq, DIM);
    kp_k<<<dim3(SEQ, BATCH), 256, 0, stream>>>(x, Mx, Sx, kp);
    attn_k<<<dim3(DIM / 64, BATCH), 256, 0, stream>>>(Qb, Mq, Sq, kp, temp, attnv);

    // ---- MLP path ----
    gemm_mfma<true, u16><<<dim3(HID / 128, MTOT / 128), 256, 0, stream>>>(
        xb, fc1wb, fc1b, h1, MTOT, HID, DIM);
    dwconv_v<<<dim3(3, 128, BATCH), 128, 0, stream>>>(h1, dww, dwb, gamma, h2);
    gemm_mfma<true, u16><<<dim3(DIM / 128, MTOT / 128), 256, 0, stream>>>(
        h2, fc2wb, fc2b, vpreb, MTOT, DIM, HID);
    ln_out_k<<<dim3(SEQ, BATCH), 256, 0, stream>>>(vpreb, lnw, lnb, attnv, out, out2);
}

// Round 4
// 411.447 us; speedup vs baseline: 7.1503x; 1.1288x over previous
//
#include <hip/hip_runtime.h>

// B=16, N=1024 (=32x32), DIM=768, HEADS=8, CH=96, HIDDEN=3072.
#define BATCH 16
#define SEQ   1024
#define DIM   768
#define NHEAD 8
#define CHD   96
#define HID   3072
#define MTOT  (BATCH * SEQ)   // 16384

using u16 = unsigned short;
typedef __attribute__((ext_vector_type(8))) short bf16x8;   // 8 bf16 = 4 VGPRs
typedef __attribute__((ext_vector_type(4))) float f32x4;

#define AS1 __attribute__((address_space(1)))
#define AS3 __attribute__((address_space(3)))

__device__ inline float bf2f(u16 u) {
    union { unsigned int i; float f; } v; v.i = ((unsigned int)u) << 16; return v.f;
}
__device__ inline u16 f2bf(float f) {
    union { float f; unsigned int i; } v; v.f = f;
    unsigned int r = v.i + 0x7FFFu + ((v.i >> 16) & 1u);
    return (u16)(r >> 16);
}

__device__ inline void gld16(const void* g, void* l) {
    __builtin_amdgcn_global_load_lds((AS1 const void*)g, (AS3 void*)l, 16, 0, 0);
}

// ---------------------------------------------------------------------------
// 256x256 bf16 MFMA GEMM, deep pipeline. C[m,n] = sum_k A[m,k]*B[n,k] (+bias).
// A: MxK row-major bf16, B: NxK row-major bf16 (weights W[n][k]).
// 512 threads = 8 waves (2 wave-rows x 4 wave-cols), per-wave 128x64 output.
// K-tiles of BK=32 in a 4-slot LDS ring (4 x (16KB A + 16KB B) = 128 KB).
// Stage tile T+3 while computing tile T; per-wave counted vmcnt at tile entry
// (steady-state vmcnt(8), never 0); ONE raw s_barrier per tile.
// LDS XOR swizzle: physical colB = logical colB ^ ((row&3)<<4), realized by
// pre-swizzling the *global source* column (global_load_lds writes linearly).
// ---------------------------------------------------------------------------
template <bool HAS_BIAS>
__global__ __launch_bounds__(512, 2) void gemm256(const u16* __restrict__ A,
                                                  const u16* __restrict__ B,
                                                  const float* __restrict__ bias,
                                                  u16* __restrict__ C,
                                                  int M, int N, int K) {
    __shared__ u16 lds[4][2][256 * 32];   // [ring][A/B][row*32 + k], 128 KB
    const int tid = threadIdx.x;
    const int lane = tid & 63;
    const int wid = tid >> 6;             // 0..7
    const int wm = (wid >> 2) << 7;       // 0 or 128
    const int wn = (wid & 3) << 6;        // 0,64,128,192

    // XCD-chunked bijective swizzle (caller guarantees nwg % 8 == 0).
    const int nwg = gridDim.x;
    const int wg = blockIdx.x;
    const int lid = (wg & 7) * (nwg >> 3) + (wg >> 3);
    const int nbx = N >> 8;               // n-blocks (N/256)
    const int mb = lid / nbx, nb = lid - mb * nbx;
    const int m0 = mb << 8, n0 = nb << 8;

    // Staging geometry: issue q in {0,1} per operand covers rows q*128 + tid/4,
    // physical col bytes (tid&3)*16. Pre-swizzle the global column.
    const int srow = tid >> 2;                                // 0..127
    const int scol = (((tid & 3) << 4) ^ ((srow & 3) << 4)) >> 1;  // logical elems
    const u16* pa0 = A + (size_t)(m0 + srow) * K + scol;
    const u16* pa1 = A + (size_t)(m0 + 128 + srow) * K + scol;
    const u16* pb0 = B + (size_t)(n0 + srow) * K + scol;
    const u16* pb1 = B + (size_t)(n0 + 128 + srow) * K + scol;

    // Fragment-read geometry (16x16x32 A/B layout: row = lrow, k-slot by lane>>4).
    const int lrow = lane & 15;
    const int swcol = ((((lane >> 4) << 4) ^ ((lrow & 3) << 4)) >> 1); // elems

    f32x4 acc[8][4] = {};

#define STAGE256(bf, kk) do {                                   \
    gld16(pa0 + (kk), &lds[bf][0][tid * 8]);                    \
    gld16(pa1 + (kk), &lds[bf][0][(512 + tid) * 8]);            \
    gld16(pb0 + (kk), &lds[bf][1][tid * 8]);                    \
    gld16(pb1 + (kk), &lds[bf][1][(512 + tid) * 8]);            \
} while (0)

    const int NT = K >> 5;                // K/32 tiles (>= 24 here)
    STAGE256(0, 0);
    STAGE256(1, 32);
    STAGE256(2, 64);

    for (int T = 0; T < NT; ++T) {
        const int rem = NT - 1 - T;
        // Own loads for tile T landed; tiles T+1,T+2 (4 issues each) may fly.
        if (rem >= 2)      asm volatile("s_waitcnt vmcnt(8)" ::: "memory");
        else if (rem == 1) asm volatile("s_waitcnt vmcnt(4)" ::: "memory");
        else               asm volatile("s_waitcnt vmcnt(0)" ::: "memory");
        __builtin_amdgcn_sched_barrier(0);
        __builtin_amdgcn_s_barrier();     // all waves' tile-T data in LDS; all
                                          // waves' tile-(T-1) reads drained
        __builtin_amdgcn_sched_barrier(0);

        const u16* Ab = lds[T & 3][0];
        const u16* Bb = lds[T & 3][1];

        bf16x8 bfr[4], afr[4];
#pragma unroll
        for (int j = 0; j < 4; ++j)
            bfr[j] = *(const bf16x8*)&Bb[(wn + j * 16 + lrow) * 32 + swcol];
#pragma unroll
        for (int i = 0; i < 4; ++i)
            afr[i] = *(const bf16x8*)&Ab[(wm + i * 16 + lrow) * 32 + swcol];

        if (T + 3 < NT) STAGE256((T + 3) & 3, (T + 3) * 32);

        asm volatile("s_waitcnt lgkmcnt(0)" ::: "memory");
        __builtin_amdgcn_sched_barrier(0);
        __builtin_amdgcn_s_setprio(1);
#pragma unroll
        for (int i = 0; i < 4; ++i)
#pragma unroll
            for (int j = 0; j < 4; ++j)
                acc[i][j] = __builtin_amdgcn_mfma_f32_16x16x32_bf16(afr[i], bfr[j], acc[i][j], 0, 0, 0);
        __builtin_amdgcn_s_setprio(0);

        bf16x8 afr2[4];
#pragma unroll
        for (int i = 0; i < 4; ++i)
            afr2[i] = *(const bf16x8*)&Ab[(wm + (i + 4) * 16 + lrow) * 32 + swcol];
        asm volatile("s_waitcnt lgkmcnt(0)" ::: "memory");
        __builtin_amdgcn_sched_barrier(0);
        __builtin_amdgcn_s_setprio(1);
#pragma unroll
        for (int i = 0; i < 4; ++i)
#pragma unroll
            for (int j = 0; j < 4; ++j)
                acc[i + 4][j] = __builtin_amdgcn_mfma_f32_16x16x32_bf16(afr2[i], bfr[j], acc[i + 4][j], 0, 0, 0);
        __builtin_amdgcn_s_setprio(0);
    }
#undef STAGE256

    // C/D layout: col = lane&15, row = (lane>>4)*4 + reg  [m89/m91 verified]
    const int crow = (lane >> 4) << 2, ccol = lane & 15;
#pragma unroll
    for (int i = 0; i < 8; ++i) {
        const int gm = m0 + wm + i * 16 + crow;
#pragma unroll
        for (int j = 0; j < 4; ++j) {
            const int gn = n0 + wn + j * 16 + ccol;
            const float bv = HAS_BIAS ? bias[gn] : 0.f;
#pragma unroll
            for (int r = 0; r < 4; ++r)
                C[(size_t)(gm + r) * N + gn] = f2bf(acc[i][j][r] + bv);
        }
    }
}

// fp32 -> bf16 bulk convert (4 elems/thread)
__global__ __launch_bounds__(256) void cvt_f2bf(const float* __restrict__ in,
                                                u16* __restrict__ out, int n4) {
    int i = blockIdx.x * 256 + threadIdx.x;
    if (i >= n4) return;
    float4 v = reinterpret_cast<const float4*>(in)[i];
    ushort4 o;
    o.x = f2bf(v.x); o.y = f2bf(v.y); o.z = f2bf(v.z); o.w = f2bf(v.w);
    reinterpret_cast<ushort4*>(out)[i] = o;
}

// Column-wise (over n=0..1023) online softmax stats (max, sumexp) per (b, j).
template <typename T>
__global__ __launch_bounds__(256) void colsm_stats(const T* __restrict__ X,
                                                   float* __restrict__ Mo,
                                                   float* __restrict__ So,
                                                   int ncols) {
    const int tid = threadIdx.x, lane = tid & 63, chunk = tid >> 6;
    const int b = blockIdx.y;
    const int j = blockIdx.x * 64 + lane;
    const T* p = X + (size_t)b * SEQ * ncols + j;
    float m = -3.0e38f, s = 0.f;
    const int nEnd = (chunk + 1) << 8;
    for (int n = chunk << 8; n < nEnd; ++n) {
        float raw;
        if constexpr (sizeof(T) == 2) raw = bf2f(p[(size_t)n * ncols]);
        else raw = p[(size_t)n * ncols];
        float nm = fmaxf(m, raw);
        s = s * __expf(m - nm) + __expf(raw - nm);
        m = nm;
    }
    __shared__ float ms[4][64], ss[4][64];
    ms[chunk][lane] = m; ss[chunk][lane] = s;
    __syncthreads();
    if (tid < 64) {
        float M = fmaxf(fmaxf(ms[0][lane], ms[1][lane]), fmaxf(ms[2][lane], ms[3][lane]));
        float S = ss[0][lane] * __expf(ms[0][lane] - M) + ss[1][lane] * __expf(ms[1][lane] - M) +
                  ss[2][lane] * __expf(ms[2][lane] - M) + ss[3][lane] * __expf(ms[3][lane] - M);
        Mo[b * ncols + j] = M;
        So[b * ncols + j] = S;
    }
}

// kp[b,h,n] = mean_c softmax_n(x)[b,n,h*96+c]
__global__ __launch_bounds__(256) void kp_k(const float* __restrict__ x,
                                            const float* __restrict__ Mx,
                                            const float* __restrict__ Sx,
                                            float* __restrict__ kp) {
    const int n = blockIdx.x, b = blockIdx.y, tid = threadIdx.x;
    __shared__ float p[DIM];
    const float* row = x + ((size_t)b * SEQ + n) * DIM;
#pragma unroll
    for (int q = 0; q < 3; ++q) {
        int j = tid + (q << 8);
        p[j] = __expf(row[j] - Mx[b * DIM + j]) / Sx[b * DIM + j];
    }
    __syncthreads();
    if (tid < NHEAD) {
        float s = 0.f;
        for (int c = 0; c < CHD; ++c) s += p[tid * CHD + c];
        kp[((size_t)b * NHEAD + tid) * SEQ + n] = s * (1.f / (float)CHD);
    }
}

// attn[b,j] = sigmoid( (1/Sq) * sum_n exp(Q[b,n,j]-Mq) * kp[b,h(j),n] ) * temp[h]
__global__ __launch_bounds__(256) void attn_k(const u16* __restrict__ Q,
                                              const float* __restrict__ Mq,
                                              const float* __restrict__ Sq,
                                              const float* __restrict__ kp,
                                              const float* __restrict__ temp,
                                              float* __restrict__ attnv) {
    const int tid = threadIdx.x, lane = tid & 63, chunk = tid >> 6;
    const int b = blockIdx.y;
    const int j = blockIdx.x * 64 + lane;
    const int h = j / CHD;
    const float mq = Mq[b * DIM + j];
    const u16* qp = Q + (size_t)b * SEQ * DIM + j;
    const float* kpp = kp + ((size_t)b * NHEAD + h) * SEQ;
    float acc = 0.f;
    const int nEnd = (chunk + 1) << 8;
    for (int n = chunk << 8; n < nEnd; ++n)
        acc += __expf(bf2f(qp[(size_t)n * DIM]) - mq) * kpp[n];
    __shared__ float accs[4][64];
    accs[chunk][lane] = acc;
    __syncthreads();
    if (tid < 64) {
        float a = accs[0][lane] + accs[1][lane] + accs[2][lane] + accs[3][lane];
        float z = a / Sq[b * DIM + j];
        attnv[b * DIM + j] = temp[h] / (1.f + __expf(-z));
    }
}

// Depthwise 3x3 + residual + gamma, vectorized: each thread owns 8 channels
// (16B loads) x 8 consecutive x-positions. Residual/bias folded into weights.
__global__ __launch_bounds__(128) void dwconv_v(const u16* __restrict__ h1,
                                                const float* __restrict__ w,
                                                const float* __restrict__ dwb,
                                                const float* __restrict__ gamma,
                                                u16* __restrict__ h2) {
    const int g = blockIdx.x * 128 + threadIdx.x;   // ch8 group, 0..383
    const int y = blockIdx.y >> 2;                  // 0..31
    const int xw0 = (blockIdx.y & 3) << 3;          // 0,8,16,24
    const int b = blockIdx.z;
    const int ch0 = g << 3;

    float wreg[8][9], bias2[8];
#pragma unroll
    for (int c = 0; c < 8; ++c) {
        const float gm = gamma[ch0 + c];
#pragma unroll
        for (int k = 0; k < 9; ++k) wreg[c][k] = gm * w[(ch0 + c) * 9 + k];
        wreg[c][4] += 1.0f;                 // residual fold (center tap)
        bias2[c] = gm * dwb[ch0 + c];
    }

    float acc[8][8];
#pragma unroll
    for (int xo = 0; xo < 8; ++xo)
#pragma unroll
        for (int c = 0; c < 8; ++c) acc[xo][c] = bias2[c];

    const u16* base = h1 + (size_t)b * SEQ * HID + ch0;
#pragma unroll
    for (int dy = 0; dy < 3; ++dy) {
        const int yy = y + dy - 1;
        if ((unsigned)yy > 31u) continue;           // wave-uniform
#pragma unroll
        for (int cr = -1; cr <= 8; ++cr) {          // column rel to xw0
            const int col = xw0 + cr;
            if ((unsigned)col > 31u) continue;      // wave-uniform
            const uint4 v = *reinterpret_cast<const uint4*>(
                base + (size_t)((yy << 5) + col) * HID);
            float f[8];
            f[0] = bf2f((u16)(v.x & 0xffff)); f[1] = bf2f((u16)(v.x >> 16));
            f[2] = bf2f((u16)(v.y & 0xffff)); f[3] = bf2f((u16)(v.y >> 16));
            f[4] = bf2f((u16)(v.z & 0xffff)); f[5] = bf2f((u16)(v.z >> 16));
            f[6] = bf2f((u16)(v.w & 0xffff)); f[7] = bf2f((u16)(v.w >> 16));
            const int xlo = cr > 0 ? cr - 1 : 0;
            const int xhi = cr < 7 ? cr + 1 : 7;
#pragma unroll
            for (int xo = 0; xo < 8; ++xo) {
                if (xo < xlo || xo > xhi) continue; // compile-time after unroll
                const int dx = cr - xo + 1;
#pragma unroll
                for (int c = 0; c < 8; ++c)
                    acc[xo][c] += f[c] * wreg[c][dy * 3 + dx];
            }
        }
    }

#pragma unroll
    for (int xo = 0; xo < 8; ++xo) {
        const int n = (y << 5) + xw0 + xo;
        uint4 o;
        o.x = (unsigned)f2bf(acc[xo][0]) | ((unsigned)f2bf(acc[xo][1]) << 16);
        o.y = (unsigned)f2bf(acc[xo][2]) | ((unsigned)f2bf(acc[xo][3]) << 16);
        o.z = (unsigned)f2bf(acc[xo][4]) | ((unsigned)f2bf(acc[xo][5]) << 16);
        o.w = (unsigned)f2bf(acc[xo][6]) | ((unsigned)f2bf(acc[xo][7]) << 16);
        *reinterpret_cast<uint4*>(h2 + ((size_t)b * SEQ + n) * HID + ch0) = o;
    }
}

// LayerNorm(768) then out[b,n,j] = attn[b,j]*v ; out2[b,h,n,c] = same value.
__global__ __launch_bounds__(256) void ln_out_k(const u16* __restrict__ vpre,
                                                const float* __restrict__ lnw,
                                                const float* __restrict__ lnb,
                                                const float* __restrict__ attnv,
                                                float* __restrict__ out,
                                                float* __restrict__ out2) {
    const int n = blockIdx.x, b = blockIdx.y, tid = threadIdx.x;
    __shared__ float red[4];
    const u16* row = vpre + ((size_t)b * SEQ + n) * DIM;
    float v[3];
    float s = 0.f;
#pragma unroll
    for (int q = 0; q < 3; ++q) { v[q] = bf2f(row[tid + (q << 8)]); s += v[q]; }
#pragma unroll
    for (int o = 32; o; o >>= 1) s += __shfl_down(s, o, 64);
    if ((tid & 63) == 0) red[tid >> 6] = s;
    __syncthreads();
    const float mu = (red[0] + red[1] + red[2] + red[3]) * (1.f / (float)DIM);
    __syncthreads();
    float vs = 0.f;
#pragma unroll
    for (int q = 0; q < 3; ++q) { float d = v[q] - mu; vs += d * d; }
#pragma unroll
    for (int o = 32; o; o >>= 1) vs += __shfl_down(vs, o, 64);
    if ((tid & 63) == 0) red[tid >> 6] = vs;
    __syncthreads();
    const float rstd = rsqrtf((red[0] + red[1] + red[2] + red[3]) * (1.f / (float)DIM) + 1e-5f);
    const float* at = attnv + b * DIM;
    float* orow = out + ((size_t)b * SEQ + n) * DIM;
#pragma unroll
    for (int q = 0; q < 3; ++q) {
        int j = tid + (q << 8);
        float o = (v[q] - mu) * rstd * lnw[j] + lnb[j];
        o *= at[j];
        orow[j] = o;
        int h = j / CHD, c = j - h * CHD;
        out2[(((size_t)b * NHEAD + h) * SEQ + n) * CHD + c] = o;
    }
}

extern "C" void kernel_launch(void* const* d_in, const int* in_sizes, int n_in,
                              void* d_out, int out_size, void* d_ws, size_t ws_size,
                              hipStream_t stream) {
    const float* x     = (const float*)d_in[0];
    const float* Wq    = (const float*)d_in[1];
    const float* temp  = (const float*)d_in[2];
    const float* fc1w  = (const float*)d_in[3];
    const float* fc1b  = (const float*)d_in[4];
    const float* dww   = (const float*)d_in[5];
    const float* dwb   = (const float*)d_in[6];
    const float* gamma = (const float*)d_in[7];
    const float* fc2w  = (const float*)d_in[8];
    const float* fc2b  = (const float*)d_in[9];
    const float* lnw   = (const float*)d_in[10];
    const float* lnb   = (const float*)d_in[11];

    float* out  = (float*)d_out;
    float* out2 = out + (size_t)BATCH * SEQ * DIM;

    char* ws = (char*)d_ws;
    u16* xb     = (u16*)ws;
    u16* h1     = (u16*)(ws + 25165824);
    u16* Wqb    = (u16*)(ws + 125829120);
    u16* fc1wb  = (u16*)(ws + 127008768);
    u16* fc2wb  = (u16*)(ws + 131727360);
    float* Mx   = (float*)(ws + 136445952);
    float* Sx   = Mx + BATCH * DIM;
    float* Mq   = Sx + BATCH * DIM;
    float* Sq   = Mq + BATCH * DIM;
    float* kp   = Sq + BATCH * DIM;            // 16*8*1024
    float* attnv = kp + BATCH * NHEAD * SEQ;   // 16*768
    u16* vpreb  = xb;                          // reuse after fc1 gemm consumed xb

    // Qb lives in d_out until attn_k consumes it; then dwconv overwrites d_out
    // with h2; fc2 consumes h2 before ln_out writes out/out2.
    u16* Qb = (u16*)d_out;
    u16* h2 = (u16*)d_out;

    // ---- fp32 -> bf16 conversions ----
    cvt_f2bf<<<(MTOT * DIM / 4 + 255) / 256, 256, 0, stream>>>(x, xb, MTOT * DIM / 4);
    cvt_f2bf<<<(DIM * DIM / 4 + 255) / 256, 256, 0, stream>>>(Wq, Wqb, DIM * DIM / 4);
    cvt_f2bf<<<(HID * DIM / 4 + 255) / 256, 256, 0, stream>>>(fc1w, fc1wb, HID * DIM / 4);
    cvt_f2bf<<<(DIM * HID / 4 + 255) / 256, 256, 0, stream>>>(fc2w, fc2wb, DIM * HID / 4);

    // ---- attention path ----  (grids: (M/256)*(N/256), all % 8 == 0)
    gemm256<false><<<(MTOT / 256) * (DIM / 256), 512, 0, stream>>>(
        xb, Wqb, nullptr, Qb, MTOT, DIM, DIM);
    colsm_stats<float><<<dim3(DIM / 64, BATCH), 256, 0, stream>>>(x, Mx, Sx, DIM);
    colsm_stats<u16><<<dim3(DIM / 64, BATCH), 256, 0, stream>>>(Qb, Mq, Sq, DIM);
    kp_k<<<dim3(SEQ, BATCH), 256, 0, stream>>>(x, Mx, Sx, kp);
    attn_k<<<dim3(DIM / 64, BATCH), 256, 0, stream>>>(Qb, Mq, Sq, kp, temp, attnv);

    // ---- MLP path ----
    gemm256<true><<<(MTOT / 256) * (HID / 256), 512, 0, stream>>>(
        xb, fc1wb, fc1b, h1, MTOT, HID, DIM);
    dwconv_v<<<dim3(3, 128, BATCH), 128, 0, stream>>>(h1, dww, dwb, gamma, h2);
    gemm256<true><<<(MTOT / 256) * (DIM / 256), 512, 0, stream>>>(
        h2, fc2wb, fc2b, vpreb, MTOT, DIM, HID);
    ln_out_k<<<dim3(SEQ, BATCH), 256, 0, stream>>>(vpreb, lnw, lnb, attnv, out, out2);
}

// Round 5
// 408.631 us; speedup vs baseline: 7.1996x; 1.0069x over previous
//
#include <hip/hip_runtime.h>

// B=16, N=1024 (=32x32), DIM=768, HEADS=8, CH=96, HIDDEN=3072.
#define BATCH 16
#define SEQ   1024
#define DIM   768
#define NHEAD 8
#define CHD   96
#define HID   3072
#define MTOT  (BATCH * SEQ)   // 16384

using u16 = unsigned short;
typedef __attribute__((ext_vector_type(8))) short bf16x8;   // 8 bf16 = 4 VGPRs
typedef __attribute__((ext_vector_type(4))) float f32x4;

#define AS1 __attribute__((address_space(1)))
#define AS3 __attribute__((address_space(3)))

__device__ inline float bf2f(u16 u) {
    union { unsigned int i; float f; } v; v.i = ((unsigned int)u) << 16; return v.f;
}
__device__ inline u16 f2bf(float f) {
    union { float f; unsigned int i; } v; v.f = f;
    unsigned int r = v.i + 0x7FFFu + ((v.i >> 16) & 1u);
    return (u16)(r >> 16);
}

__device__ inline void gld16(const void* g, void* l) {
    __builtin_amdgcn_global_load_lds((AS1 const void*)g, (AS3 void*)l, 16, 0, 0);
}

// ---------------------------------------------------------------------------
// 256x256 bf16 MFMA GEMM, 4-phase-per-K-tile interleave (m201-style).
// C[m,n] = sum_k A[m,k]*B[n,k] (+bias). A: MxK, B: NxK, both row-major bf16.
// 512 threads = 8 waves (2 wave-rows x 4 wave-cols), per-wave 128x64 output.
// BK=64, double-buffered LDS (2 x (32KB A + 32KB B) = 128 KB).
// Per K-tile: 4 phases, each {ds_read frags | issue staging gld | barrier |
// lgkmcnt(0) | setprio(1) 16 MFMA setprio(0) | barrier}; staging for tile t+1
// is front-loaded into phases 1-2 (A then B) so the single vmcnt(0)+barrier
// at the tile boundary finds the loads already landed (~1500cy > HBM 900cy).
// LDS swizzle: physical byte col = logical ^ ((row&7)<<4)  (8 slots in the
// 128-B row -> residual 2-way conflict = free). Realized on the staging side
// by pre-swizzling the *global source* column (global_load_lds writes
// linearly, rule #21) and on the read side with the same XOR.
// ---------------------------------------------------------------------------
template <bool HAS_BIAS>
__global__ __launch_bounds__(512, 2) void gemm256(const u16* __restrict__ A,
                                                  const u16* __restrict__ B,
                                                  const float* __restrict__ bias,
                                                  u16* __restrict__ C,
                                                  int M, int N, int K) {
    __shared__ u16 lds[2][2][256 * 64];   // [dbuf][A/B][row*64+col], 128 KB
    const int tid = threadIdx.x;
    const int lane = tid & 63;
    const int wid = tid >> 6;             // 0..7
    const int wm = (wid >> 2) << 7;       // 0 or 128
    const int wn = (wid & 3) << 6;        // 0,64,128,192

    // XCD-chunked bijective swizzle (caller guarantees nwg % 8 == 0).
    const int nwg = gridDim.x;
    const int wg = blockIdx.x;
    const int lid = (wg & 7) * (nwg >> 3) + (wg >> 3);
    const int nbx = N >> 8;
    const int mb = lid / nbx, nb = lid - mb * nbx;
    const int m0 = mb << 8, n0 = nb << 8;

    // ---- staging geometry (per thread: one 16B chunk per 64-row group) ----
    const int srow = tid >> 3;                                 // 0..63
    const int sce = ((tid & 7) << 3) ^ ((srow & 7) << 3);      // src col elems
    const u16* pa = A + (size_t)(m0 + srow) * K + sce;
    const u16* pb = B + (size_t)(n0 + srow) * K + sce;
    const size_t gstep = (size_t)64 * K;                       // 64-row stride

#define STAGE_OP(dst, p, kb) do {                               \
    gld16((p) + (kb),             (dst) + tid * 8);             \
    gld16((p) + (kb) + gstep,     (dst) + 4096 + tid * 8);      \
    gld16((p) + (kb) + 2 * gstep, (dst) + 8192 + tid * 8);      \
    gld16((p) + (kb) + 3 * gstep, (dst) + 12288 + tid * 8);     \
} while (0)

    // ---- fragment-read geometry ----
    const int lrow = lane & 15;
    const int swz = (lrow & 7) << 4;                           // byte swizzle
    const int cb0 = (((lane >> 4) << 4) ^ swz) >> 1;           // ks=0 col elems
    const int cb1 = ((64 | ((lane >> 4) << 4)) ^ swz) >> 1;    // ks=1 col elems

    f32x4 acc[8][4] = {};

    const int NT = K >> 6;                // K/64 tiles
    STAGE_OP(&lds[0][0][0], pa, 0);
    STAGE_OP(&lds[0][1][0], pb, 0);
    asm volatile("s_waitcnt vmcnt(0)" ::: "memory");
    __builtin_amdgcn_s_barrier();

    for (int t = 0; t < NT; ++t) {
        const u16* Ab = lds[t & 1][0];
        const u16* Bb = lds[t & 1][1];
        u16* An = &lds[(t + 1) & 1][0][0];
        u16* Bn = &lds[(t + 1) & 1][1][0];
        const size_t kb = (size_t)(t + 1) << 6;
        const bool pre = (t + 1 < NT);

        bf16x8 b0[4], b1[4], af[4];
        // ---------- phase 1: B(ks0) + A(rows 0-63, ks0); stage A(t+1) ----------
#pragma unroll
        for (int j = 0; j < 4; ++j) b0[j] = *(const bf16x8*)&Bb[(wn + j * 16 + lrow) * 64 + cb0];
#pragma unroll
        for (int i = 0; i < 4; ++i) af[i] = *(const bf16x8*)&Ab[(wm + i * 16 + lrow) * 64 + cb0];
        if (pre) STAGE_OP(An, pa, kb);
        __builtin_amdgcn_s_barrier();
        asm volatile("s_waitcnt lgkmcnt(0)" ::: "memory");
        __builtin_amdgcn_sched_barrier(0);
        __builtin_amdgcn_s_setprio(1);
#pragma unroll
        for (int i = 0; i < 4; ++i)
#pragma unroll
            for (int j = 0; j < 4; ++j)
                acc[i][j] = __builtin_amdgcn_mfma_f32_16x16x32_bf16(af[i], b0[j], acc[i][j], 0, 0, 0);
        __builtin_amdgcn_s_setprio(0);
        __builtin_amdgcn_s_barrier();

        // ---------- phase 2: A(rows 64-127, ks0); stage B(t+1) ----------
#pragma unroll
        for (int i = 0; i < 4; ++i) af[i] = *(const bf16x8*)&Ab[(wm + 64 + i * 16 + lrow) * 64 + cb0];
        if (pre) STAGE_OP(Bn, pb, kb);
        __builtin_amdgcn_s_barrier();
        asm volatile("s_waitcnt lgkmcnt(0)" ::: "memory");
        __builtin_amdgcn_sched_barrier(0);
        __builtin_amdgcn_s_setprio(1);
#pragma unroll
        for (int i = 0; i < 4; ++i)
#pragma unroll
            for (int j = 0; j < 4; ++j)
                acc[i + 4][j] = __builtin_amdgcn_mfma_f32_16x16x32_bf16(af[i], b0[j], acc[i + 4][j], 0, 0, 0);
        __builtin_amdgcn_s_setprio(0);
        __builtin_amdgcn_s_barrier();

        // ---------- phase 3: B(ks1) + A(rows 0-63, ks1) ----------
#pragma unroll
        for (int j = 0; j < 4; ++j) b1[j] = *(const bf16x8*)&Bb[(wn + j * 16 + lrow) * 64 + cb1];
#pragma unroll
        for (int i = 0; i < 4; ++i) af[i] = *(const bf16x8*)&Ab[(wm + i * 16 + lrow) * 64 + cb1];
        __builtin_amdgcn_s_barrier();
        asm volatile("s_waitcnt lgkmcnt(0)" ::: "memory");
        __builtin_amdgcn_sched_barrier(0);
        __builtin_amdgcn_s_setprio(1);
#pragma unroll
        for (int i = 0; i < 4; ++i)
#pragma unroll
            for (int j = 0; j < 4; ++j)
                acc[i][j] = __builtin_amdgcn_mfma_f32_16x16x32_bf16(af[i], b1[j], acc[i][j], 0, 0, 0);
        __builtin_amdgcn_s_setprio(0);
        __builtin_amdgcn_s_barrier();

        // ---------- phase 4: A(rows 64-127, ks1); boundary drain ----------
#pragma unroll
        for (int i = 0; i < 4; ++i) af[i] = *(const bf16x8*)&Ab[(wm + 64 + i * 16 + lrow) * 64 + cb1];
        __builtin_amdgcn_s_barrier();
        asm volatile("s_waitcnt lgkmcnt(0)" ::: "memory");
        __builtin_amdgcn_sched_barrier(0);
        __builtin_amdgcn_s_setprio(1);
#pragma unroll
        for (int i = 0; i < 4; ++i)
#pragma unroll
            for (int j = 0; j < 4; ++j)
                acc[i + 4][j] = __builtin_amdgcn_mfma_f32_16x16x32_bf16(af[i], b1[j], acc[i + 4][j], 0, 0, 0);
        __builtin_amdgcn_s_setprio(0);
        asm volatile("s_waitcnt vmcnt(0)" ::: "memory");   // t+1's stages landed
        __builtin_amdgcn_sched_barrier(0);
        __builtin_amdgcn_s_barrier();
    }
#undef STAGE_OP

    // C/D layout: col = lane&15, row = (lane>>4)*4 + reg  [m89/m91 verified]
    const int crow = (lane >> 4) << 2, ccol = lane & 15;
#pragma unroll
    for (int i = 0; i < 8; ++i) {
        const int gm = m0 + wm + i * 16 + crow;
#pragma unroll
        for (int j = 0; j < 4; ++j) {
            const int gn = n0 + wn + j * 16 + ccol;
            const float bv = HAS_BIAS ? bias[gn] : 0.f;
#pragma unroll
            for (int r = 0; r < 4; ++r)
                C[(size_t)(gm + r) * N + gn] = f2bf(acc[i][j][r] + bv);
        }
    }
}

// fp32 -> bf16 bulk convert (4 elems/thread)
__global__ __launch_bounds__(256) void cvt_f2bf(const float* __restrict__ in,
                                                u16* __restrict__ out, int n4) {
    int i = blockIdx.x * 256 + threadIdx.x;
    if (i >= n4) return;
    float4 v = reinterpret_cast<const float4*>(in)[i];
    ushort4 o;
    o.x = f2bf(v.x); o.y = f2bf(v.y); o.z = f2bf(v.z); o.w = f2bf(v.w);
    reinterpret_cast<ushort4*>(out)[i] = o;
}

// Column-wise (over n=0..1023) online softmax stats (max, sumexp) per (b, j).
template <typename T>
__global__ __launch_bounds__(256) void colsm_stats(const T* __restrict__ X,
                                                   float* __restrict__ Mo,
                                                   float* __restrict__ So,
                                                   int ncols) {
    const int tid = threadIdx.x, lane = tid & 63, chunk = tid >> 6;
    const int b = blockIdx.y;
    const int j = blockIdx.x * 64 + lane;
    const T* p = X + (size_t)b * SEQ * ncols + j;
    float m = -3.0e38f, s = 0.f;
    const int nEnd = (chunk + 1) << 8;
    for (int n = chunk << 8; n < nEnd; ++n) {
        float raw;
        if constexpr (sizeof(T) == 2) raw = bf2f(p[(size_t)n * ncols]);
        else raw = p[(size_t)n * ncols];
        float nm = fmaxf(m, raw);
        s = s * __expf(m - nm) + __expf(raw - nm);
        m = nm;
    }
    __shared__ float ms[4][64], ss[4][64];
    ms[chunk][lane] = m; ss[chunk][lane] = s;
    __syncthreads();
    if (tid < 64) {
        float M = fmaxf(fmaxf(ms[0][lane], ms[1][lane]), fmaxf(ms[2][lane], ms[3][lane]));
        float S = ss[0][lane] * __expf(ms[0][lane] - M) + ss[1][lane] * __expf(ms[1][lane] - M) +
                  ss[2][lane] * __expf(ms[2][lane] - M) + ss[3][lane] * __expf(ms[3][lane] - M);
        Mo[b * ncols + j] = M;
        So[b * ncols + j] = S;
    }
}

// kp[b,h,n] = mean_c softmax_n(x)[b,n,h*96+c]
__global__ __launch_bounds__(256) void kp_k(const float* __restrict__ x,
                                            const float* __restrict__ Mx,
                                            const float* __restrict__ Sx,
                                            float* __restrict__ kp) {
    const int n = blockIdx.x, b = blockIdx.y, tid = threadIdx.x;
    __shared__ float p[DIM];
    const float* row = x + ((size_t)b * SEQ + n) * DIM;
#pragma unroll
    for (int q = 0; q < 3; ++q) {
        int j = tid + (q << 8);
        p[j] = __expf(row[j] - Mx[b * DIM + j]) / Sx[b * DIM + j];
    }
    __syncthreads();
    if (tid < NHEAD) {
        float s = 0.f;
        for (int c = 0; c < CHD; ++c) s += p[tid * CHD + c];
        kp[((size_t)b * NHEAD + tid) * SEQ + n] = s * (1.f / (float)CHD);
    }
}

// attn[b,j] = sigmoid( (1/Sq) * sum_n exp(Q[b,n,j]-Mq) * kp[b,h(j),n] ) * temp[h]
__global__ __launch_bounds__(256) void attn_k(const u16* __restrict__ Q,
                                              const float* __restrict__ Mq,
                                              const float* __restrict__ Sq,
                                              const float* __restrict__ kp,
                                              const float* __restrict__ temp,
                                              float* __restrict__ attnv) {
    const int tid = threadIdx.x, lane = tid & 63, chunk = tid >> 6;
    const int b = blockIdx.y;
    const int j = blockIdx.x * 64 + lane;
    const int h = j / CHD;
    const float mq = Mq[b * DIM + j];
    const u16* qp = Q + (size_t)b * SEQ * DIM + j;
    const float* kpp = kp + ((size_t)b * NHEAD + h) * SEQ;
    float acc = 0.f;
    const int nEnd = (chunk + 1) << 8;
    for (int n = chunk << 8; n < nEnd; ++n)
        acc += __expf(bf2f(qp[(size_t)n * DIM]) - mq) * kpp[n];
    __shared__ float accs[4][64];
    accs[chunk][lane] = acc;
    __syncthreads();
    if (tid < 64) {
        float a = accs[0][lane] + accs[1][lane] + accs[2][lane] + accs[3][lane];
        float z = a / Sq[b * DIM + j];
        attnv[b * DIM + j] = temp[h] / (1.f + __expf(-z));
    }
}

// Depthwise 3x3 + residual + gamma, vectorized: each thread owns 8 channels
// (16B loads) x 8 consecutive x-positions. Residual/bias folded into weights.
__global__ __launch_bounds__(128) void dwconv_v(const u16* __restrict__ h1,
                                                const float* __restrict__ w,
                                                const float* __restrict__ dwb,
                                                const float* __restrict__ gamma,
                                                u16* __restrict__ h2) {
    const int g = blockIdx.x * 128 + threadIdx.x;   // ch8 group, 0..383
    const int y = blockIdx.y >> 2;                  // 0..31
    const int xw0 = (blockIdx.y & 3) << 3;          // 0,8,16,24
    const int b = blockIdx.z;
    const int ch0 = g << 3;

    float wreg[8][9], bias2[8];
#pragma unroll
    for (int c = 0; c < 8; ++c) {
        const float gm = gamma[ch0 + c];
#pragma unroll
        for (int k = 0; k < 9; ++k) wreg[c][k] = gm * w[(ch0 + c) * 9 + k];
        wreg[c][4] += 1.0f;                 // residual fold (center tap)
        bias2[c] = gm * dwb[ch0 + c];
    }

    float acc[8][8];
#pragma unroll
    for (int xo = 0; xo < 8; ++xo)
#pragma unroll
        for (int c = 0; c < 8; ++c) acc[xo][c] = bias2[c];

    const u16* base = h1 + (size_t)b * SEQ * HID + ch0;
#pragma unroll
    for (int dy = 0; dy < 3; ++dy) {
        const int yy = y + dy - 1;
        if ((unsigned)yy > 31u) continue;           // wave-uniform
#pragma unroll
        for (int cr = -1; cr <= 8; ++cr) {          // column rel to xw0
            const int col = xw0 + cr;
            if ((unsigned)col > 31u) continue;      // wave-uniform
            const uint4 v = *reinterpret_cast<const uint4*>(
                base + (size_t)((yy << 5) + col) * HID);
            float f[8];
            f[0] = bf2f((u16)(v.x & 0xffff)); f[1] = bf2f((u16)(v.x >> 16));
            f[2] = bf2f((u16)(v.y & 0xffff)); f[3] = bf2f((u16)(v.y >> 16));
            f[4] = bf2f((u16)(v.z & 0xffff)); f[5] = bf2f((u16)(v.z >> 16));
            f[6] = bf2f((u16)(v.w & 0xffff)); f[7] = bf2f((u16)(v.w >> 16));
            const int xlo = cr > 0 ? cr - 1 : 0;
            const int xhi = cr < 7 ? cr + 1 : 7;
#pragma unroll
            for (int xo = 0; xo < 8; ++xo) {
                if (xo < xlo || xo > xhi) continue; // compile-time after unroll
                const int dx = cr - xo + 1;
#pragma unroll
                for (int c = 0; c < 8; ++c)
                    acc[xo][c] += f[c] * wreg[c][dy * 3 + dx];
            }
        }
    }

#pragma unroll
    for (int xo = 0; xo < 8; ++xo) {
        const int n = (y << 5) + xw0 + xo;
        uint4 o;
        o.x = (unsigned)f2bf(acc[xo][0]) | ((unsigned)f2bf(acc[xo][1]) << 16);
        o.y = (unsigned)f2bf(acc[xo][2]) | ((unsigned)f2bf(acc[xo][3]) << 16);
        o.z = (unsigned)f2bf(acc[xo][4]) | ((unsigned)f2bf(acc[xo][5]) << 16);
        o.w = (unsigned)f2bf(acc[xo][6]) | ((unsigned)f2bf(acc[xo][7]) << 16);
        *reinterpret_cast<uint4*>(h2 + ((size_t)b * SEQ + n) * HID + ch0) = o;
    }
}

// LayerNorm(768) then out[b,n,j] = attn[b,j]*v ; out2[b,h,n,c] = same value.
__global__ __launch_bounds__(256) void ln_out_k(const u16* __restrict__ vpre,
                                                const float* __restrict__ lnw,
                                                const float* __restrict__ lnb,
                                                const float* __restrict__ attnv,
                                                float* __restrict__ out,
                                                float* __restrict__ out2) {
    const int n = blockIdx.x, b = blockIdx.y, tid = threadIdx.x;
    __shared__ float red[4];
    const u16* row = vpre + ((size_t)b * SEQ + n) * DIM;
    float v[3];
    float s = 0.f;
#pragma unroll
    for (int q = 0; q < 3; ++q) { v[q] = bf2f(row[tid + (q << 8)]); s += v[q]; }
#pragma unroll
    for (int o = 32; o; o >>= 1) s += __shfl_down(s, o, 64);
    if ((tid & 63) == 0) red[tid >> 6] = s;
    __syncthreads();
    const float mu = (red[0] + red[1] + red[2] + red[3]) * (1.f / (float)DIM);
    __syncthreads();
    float vs = 0.f;
#pragma unroll
    for (int q = 0; q < 3; ++q) { float d = v[q] - mu; vs += d * d; }
#pragma unroll
    for (int o = 32; o; o >>= 1) vs += __shfl_down(vs, o, 64);
    if ((tid & 63) == 0) red[tid >> 6] = vs;
    __syncthreads();
    const float rstd = rsqrtf((red[0] + red[1] + red[2] + red[3]) * (1.f / (float)DIM) + 1e-5f);
    const float* at = attnv + b * DIM;
    float* orow = out + ((size_t)b * SEQ + n) * DIM;
#pragma unroll
    for (int q = 0; q < 3; ++q) {
        int j = tid + (q << 8);
        float o = (v[q] - mu) * rstd * lnw[j] + lnb[j];
        o *= at[j];
        orow[j] = o;
        int h = j / CHD, c = j - h * CHD;
        out2[(((size_t)b * NHEAD + h) * SEQ + n) * CHD + c] = o;
    }
}

extern "C" void kernel_launch(void* const* d_in, const int* in_sizes, int n_in,
                              void* d_out, int out_size, void* d_ws, size_t ws_size,
                              hipStream_t stream) {
    const float* x     = (const float*)d_in[0];
    const float* Wq    = (const float*)d_in[1];
    const float* temp  = (const float*)d_in[2];
    const float* fc1w  = (const float*)d_in[3];
    const float* fc1b  = (const float*)d_in[4];
    const float* dww   = (const float*)d_in[5];
    const float* dwb   = (const float*)d_in[6];
    const float* gamma = (const float*)d_in[7];
    const float* fc2w  = (const float*)d_in[8];
    const float* fc2b  = (const float*)d_in[9];
    const float* lnw   = (const float*)d_in[10];
    const float* lnb   = (const float*)d_in[11];

    float* out  = (float*)d_out;
    float* out2 = out + (size_t)BATCH * SEQ * DIM;

    char* ws = (char*)d_ws;
    u16* xb     = (u16*)ws;
    u16* h1     = (u16*)(ws + 25165824);
    u16* Wqb    = (u16*)(ws + 125829120);
    u16* fc1wb  = (u16*)(ws + 127008768);
    u16* fc2wb  = (u16*)(ws + 131727360);
    float* Mx   = (float*)(ws + 136445952);
    float* Sx   = Mx + BATCH * DIM;
    float* Mq   = Sx + BATCH * DIM;
    float* Sq   = Mq + BATCH * DIM;
    float* kp   = Sq + BATCH * DIM;            // 16*8*1024
    float* attnv = kp + BATCH * NHEAD * SEQ;   // 16*768
    u16* vpreb  = xb;                          // reuse after fc1 gemm consumed xb

    // Qb lives in d_out until attn_k consumes it; then dwconv overwrites d_out
    // with h2; fc2 consumes h2 before ln_out writes out/out2.
    u16* Qb = (u16*)d_out;
    u16* h2 = (u16*)d_out;

    // ---- fp32 -> bf16 conversions ----
    cvt_f2bf<<<(MTOT * DIM / 4 + 255) / 256, 256, 0, stream>>>(x, xb, MTOT * DIM / 4);
    cvt_f2bf<<<(DIM * DIM / 4 + 255) / 256, 256, 0, stream>>>(Wq, Wqb, DIM * DIM / 4);
    cvt_f2bf<<<(HID * DIM / 4 + 255) / 256, 256, 0, stream>>>(fc1w, fc1wb, HID * DIM / 4);
    cvt_f2bf<<<(DIM * HID / 4 + 255) / 256, 256, 0, stream>>>(fc2w, fc2wb, DIM * HID / 4);

    // ---- attention path ----  (grids: (M/256)*(N/256), all % 8 == 0)
    gemm256<false><<<(MTOT / 256) * (DIM / 256), 512, 0, stream>>>(
        xb, Wqb, nullptr, Qb, MTOT, DIM, DIM);
    colsm_stats<float><<<dim3(DIM / 64, BATCH), 256, 0, stream>>>(x, Mx, Sx, DIM);
    colsm_stats<u16><<<dim3(DIM / 64, BATCH), 256, 0, stream>>>(Qb, Mq, Sq, DIM);
    kp_k<<<dim3(SEQ, BATCH), 256, 0, stream>>>(x, Mx, Sx, kp);
    attn_k<<<dim3(DIM / 64, BATCH), 256, 0, stream>>>(Qb, Mq, Sq, kp, temp, attnv);

    // ---- MLP path ----
    gemm256<true><<<(MTOT / 256) * (HID / 256), 512, 0, stream>>>(
        xb, fc1wb, fc1b, h1, MTOT, HID, DIM);
    dwconv_v<<<dim3(3, 128, BATCH), 128, 0, stream>>>(h1, dww, dwb, gamma, h2);
    gemm256<true><<<(MTOT / 256) * (DIM / 256), 512, 0, stream>>>(
        h2, fc2wb, fc2b, vpreb, MTOT, DIM, HID);
    ln_out_k<<<dim3(SEQ, BATCH), 256, 0, stream>>>(vpreb, lnw, lnb, attnv, out, out2);
}